// Round 9
// baseline (1100.296 us; speedup 1.0000x reference)
//
#include <hip/hip_runtime.h>

#define BB 64
#define TT 1024
#define HH 1024
#define II 8
#define OO 8
#define RRK 4
#define NOISE_STD 0.05f
#define ALPHA 0.2f

typedef float v4f __attribute__((ext_vector_type(4)));

// 2*log2(e): tanh argument scale so exp goes through native v_exp_f32 (2^x).
#define C2E 2.885390081777927f

// DPP-based add: acc + dpp_perm(src). VALU pipe (NOT ds_bpermute).
template<int CTRL, int RM>
__device__ __forceinline__ float dpp_add(float acc, float src) {
    int s = __builtin_amdgcn_update_dpp(0, __float_as_int(src), CTRL, RM, 0xF, true);
    return acc + __int_as_float(s);
}

// Full wave64 sum; result valid on lane 63. All-VALU (6 DPP adds).
__device__ __forceinline__ float wave_sum(float x) {
    x = dpp_add<0xB1, 0xF>(x, x);   // xor 1
    x = dpp_add<0x4E, 0xF>(x, x);   // xor 2
    x = dpp_add<0x141, 0xF>(x, x);  // row_half_mirror
    x = dpp_add<0x140, 0xF>(x, x);  // row_mirror
    x = dpp_add<0x142, 0xA>(x, x);  // row_bcast:15
    x = dpp_add<0x143, 0xC>(x, x);  // row_bcast:31
    return x;
}

// tanh(x) = 1 - 2/(1 + 2^(2x*log2e)); argument passed as 2x*log2(e).
__device__ __forceinline__ float tanh_from_l2x(float l2x) {
    float e = __builtin_amdgcn_exp2f(l2x);
    float r = __builtin_amdgcn_rcpf(e + 1.0f);
    return fmaf(-2.0f, r, 1.0f);
}

__device__ __forceinline__ v4f tanh4(v4f tg) {
    v4f r;
    r.x = tanh_from_l2x(tg.x); r.y = tanh_from_l2x(tg.y);
    r.z = tanh_from_l2x(tg.z); r.w = tanh_from_l2x(tg.w);
    return r;
}

// Barrier WITHOUT the vmcnt(0) drain of __syncthreads(): waits only LDS ops.
__device__ __forceinline__ void block_sync_lds() {
    asm volatile("s_waitcnt lgkmcnt(0)\n\ts_barrier" ::: "memory");
}

// ===========================================================================
// PATH A (needs 258 MB workspace; dispatched & verified in r6/r8):
//   pre_d_kernel : d[row][h] = alpha*(x@si*wi)[h] + sigma*noise[row][h]
//                  sbase[row][o] = d[row][:] . (wo[:,o]*so[o])   [r6 verbatim]
//   rnn_pair2    : TWO batches in the SAME wave. 32 blocks x 256 thr; each
//                  lane holds 4 h-elems of batch 2B and 4 of batch 2B+1.
//                  Per step: A(b0) A(b1) barrier B(b0) B(b1). b1's A-phase
//                  issues inside b0's write->barrier dead time; b0's B-phase
//                  covers b1's ds_read latency. Same barrier cadence & wave
//                  count as the best-measured r2 config, but TWO batch-steps
//                  per period. (r8 proved cross-wave pairing only adds convoy
//                  -- the overlap must come from within the wave.)
// ===========================================================================

__global__ __launch_bounds__(256)
void pre_d_kernel(const float* __restrict__ x, const float* __restrict__ noise,
                  const float* __restrict__ wi, const float* __restrict__ si,
                  const float* __restrict__ wo, const float* __restrict__ so,
                  float* __restrict__ d, float* __restrict__ sbase) {
    __shared__ __align__(16) float red[2][8][4][8];   // ring x row x wave x o

    const int tid  = threadIdx.x;
    const int wave = tid >> 6;
    const int lane = tid & 63;
    const int e0   = tid << 2;                        // h = e0..e0+3

    v4f wia4[II];
    #pragma unroll
    for (int i = 0; i < II; ++i)
        wia4[i] = (ALPHA * si[i]) * *(const v4f*)(wi + (size_t)i * HH + e0);

    float woa[4][OO];
    #pragma unroll
    for (int e = 0; e < 4; ++e) {
        const float4 a4 = *(const float4*)(wo + (e0 + e) * OO);
        const float4 b4 = *(const float4*)(wo + (e0 + e) * OO + 4);
        woa[e][0] = a4.x * so[0]; woa[e][1] = a4.y * so[1];
        woa[e][2] = a4.z * so[2]; woa[e][3] = a4.w * so[3];
        woa[e][4] = b4.x * so[4]; woa[e][5] = b4.y * so[5];
        woa[e][6] = b4.z * so[6]; woa[e][7] = b4.w * so[7];
    }

    const int row0 = blockIdx.x * 32;
    float4 nz[8], nzn[8];
    #pragma unroll
    for (int j = 0; j < 8; ++j)
        nz[j] = *(const float4*)(noise + (size_t)(row0 + j) * HH + e0);

    #pragma unroll
    for (int ph = 0; ph < 4; ++ph) {
        const int cur   = ph & 1;
        const int rbase = row0 + ph * 8;

        if (ph < 3) {
            #pragma unroll
            for (int j = 0; j < 8; ++j)
                nzn[j] = *(const float4*)(noise + (size_t)(rbase + 8 + j) * HH + e0);
        }

        #pragma unroll
        for (int j = 0; j < 8; ++j) {
            const int row = rbase + j;
            const float4 xr0 = *(const float4*)(x + (size_t)row * II);
            const float4 xr1 = *(const float4*)(x + (size_t)row * II + 4);
            v4f u = xr0.x * wia4[0];
            u += xr0.y * wia4[1];  u += xr0.z * wia4[2];
            u += xr0.w * wia4[3];  u += xr1.x * wia4[4];
            u += xr1.y * wia4[5];  u += xr1.z * wia4[6];
            u += xr1.w * wia4[7];
            v4f d4 = u;
            d4.x = fmaf(NOISE_STD, nz[j].x, d4.x);
            d4.y = fmaf(NOISE_STD, nz[j].y, d4.y);
            d4.z = fmaf(NOISE_STD, nz[j].z, d4.z);
            d4.w = fmaf(NOISE_STD, nz[j].w, d4.w);
            *(v4f*)(d + (size_t)row * HH + e0) = d4;

            float op[OO];
            #pragma unroll
            for (int o = 0; o < OO; ++o)
                op[o] = fmaf(d4.x, woa[0][o], fmaf(d4.y, woa[1][o],
                        fmaf(d4.z, woa[2][o], d4.w * woa[3][o])));
            #pragma unroll
            for (int o = 0; o < OO; ++o) op[o] = wave_sum(op[o]);
            if (lane == 63) {
                *(float4*)&red[cur][j][wave][0] = make_float4(op[0], op[1], op[2], op[3]);
                *(float4*)&red[cur][j][wave][4] = make_float4(op[4], op[5], op[6], op[7]);
            }
        }
        block_sync_lds();
        if (tid < 64) {
            const int j = tid >> 3, o = tid & 7;
            sbase[(rbase + j) * OO + o] = (red[cur][j][0][o] + red[cur][j][1][o]) +
                                          (red[cur][j][2][o] + red[cur][j][3][o]);
        }
        #pragma unroll
        for (int j = 0; j < 8; ++j) nz[j] = nzn[j];
    }
}

__global__ __launch_bounds__(256, 1)
void rnn_pair2(const float* __restrict__ d, const float* __restrict__ sbase,
               const float* __restrict__ mM, const float* __restrict__ nM,
               const float* __restrict__ bv, const float* __restrict__ wo,
               const float* __restrict__ so, const float* __restrict__ h0,
               float* __restrict__ out) {
    __shared__ __align__(16) float lds_v[2][TT * RRK];   // 32 KB (v logs)
    __shared__ __align__(16) float red[2][4][4][RRK];    // batch x ring x wave x q
    __shared__ __align__(16) float redc[4][40];          // preamble scratch
    __shared__ __align__(16) float amy[40];              // Am(32) | y0(8)
    __shared__ __align__(16) float chs[2][16][OO];       // post-pass carries

    const int tid  = threadIdx.x;
    const int wave = tid >> 6;
    const int lane = tid & 63;
    const int hb   = tid << 2;                   // this lane's h slice (both batches)
    const int oc   = tid & 7;
    const int bA   = blockIdx.x * 2;             // batch for stream A
    // batch for stream B = bA + 1

    // ---- loop weights (shared by both batches) ----
    v4f nrv[4], mrow[4], mac[RRK], tb2;
    {
        const float cs = ALPHA / (float)HH;
        #pragma unroll
        for (int e = 0; e < 4; ++e) {
            nrv[e]  = *(const v4f*)(nM + (size_t)(hb + e) * RRK);
            mrow[e] = cs * *(const v4f*)(mM + (size_t)(hb + e) * RRK);
        }
        #pragma unroll
        for (int q = 0; q < RRK; ++q)
            mac[q] = (v4f){mrow[0][q], mrow[1][q], mrow[2][q], mrow[3][q]};
        tb2 = C2E * *(const v4f*)(bv + hb);
    }
    v4f hA, hB, rA, rB, h0v;
    {
        h0v = *(const v4f*)(h0 + hb);
        hA = h0v; hB = h0v;
        rA = tanh4(C2E * h0v);                   // r_init = tanh(h0), no bias
        rB = rA;
    }

    // ---- preamble: Am[q][o] = sum_h (cs*m)[h][q] wo'[h,o]; y0 = h0.wo' ----
    {
        float acc[40];
        #pragma unroll
        for (int k = 0; k < 40; ++k) acc[k] = 0.0f;
        #pragma unroll
        for (int e = 0; e < 4; ++e) {
            const float4 a4 = *(const float4*)(wo + (size_t)(hb + e) * OO);
            const float4 b4 = *(const float4*)(wo + (size_t)(hb + e) * OO + 4);
            float wp[OO];
            wp[0] = a4.x * so[0]; wp[1] = a4.y * so[1];
            wp[2] = a4.z * so[2]; wp[3] = a4.w * so[3];
            wp[4] = b4.x * so[4]; wp[5] = b4.y * so[5];
            wp[6] = b4.z * so[6]; wp[7] = b4.w * so[7];
            #pragma unroll
            for (int q = 0; q < RRK; ++q) {
                const float ms = mrow[e][q];
                #pragma unroll
                for (int o = 0; o < OO; ++o)
                    acc[q * 8 + o] = fmaf(ms, wp[o], acc[q * 8 + o]);
            }
            const float hs = h0v[e];
            #pragma unroll
            for (int o = 0; o < OO; ++o)
                acc[32 + o] = fmaf(hs, wp[o], acc[32 + o]);
        }
        #pragma unroll
        for (int k = 0; k < 40; ++k) acc[k] = wave_sum(acc[k]);
        if (lane == 63) {
            #pragma unroll
            for (int k = 0; k < 10; ++k)
                *(float4*)&redc[wave][k * 4] = make_float4(acc[k*4+0], acc[k*4+1],
                                                           acc[k*4+2], acc[k*4+3]);
        }
    }
    block_sync_lds();
    if (tid < 40)
        amy[tid] = (redc[0][tid] + redc[1][tid]) + (redc[2][tid] + redc[3][tid]);
    block_sync_lds();

    // ---- d-stream prefetch rings (4 rows ahead) for both batches ----
    const float* dpA = d + (size_t)bA * (TT * HH) + hb;
    const float* dpB = dpA + (size_t)TT * HH;
    v4f dbA[4], dbB[4];
    #pragma unroll
    for (int j = 0; j < 4; ++j) {
        dbA[j] = *(const v4f*)(dpA + (size_t)j * HH);
        dbB[j] = *(const v4f*)(dpB + (size_t)j * HH);
    }

    for (int t0 = 0; t0 < TT; t0 += 4) {
        #pragma unroll
        for (int j = 0; j < 4; ++j) {
            const int t = t0 + j;

            // ---- A-phase, batch A: vp + in-wave reduce + write partials ----
            {
                v4f vp = rA.x * nrv[0];
                vp += rA.y * nrv[1]; vp += rA.z * nrv[2]; vp += rA.w * nrv[3];
                const float s0 = wave_sum(vp.x); const float s1 = wave_sum(vp.y);
                const float s2 = wave_sum(vp.z); const float s3 = wave_sum(vp.w);
                if (lane == 63)
                    *(float4*)&red[0][j][wave][0] = make_float4(s0, s1, s2, s3);
            }
            // ---- A-phase, batch B (fills A's write->barrier dead time) ----
            {
                v4f vp = rB.x * nrv[0];
                vp += rB.y * nrv[1]; vp += rB.z * nrv[2]; vp += rB.w * nrv[3];
                const float s0 = wave_sum(vp.x); const float s1 = wave_sum(vp.y);
                const float s2 = wave_sum(vp.z); const float s3 = wave_sum(vp.w);
                if (lane == 63)
                    *(float4*)&red[1][j][wave][0] = make_float4(s0, s1, s2, s3);
            }

            block_sync_lds();

            // ---- B-phase, batch A (covers batch B's ds_read latency) ----
            {
                const v4f p0 = *(const v4f*)&red[0][j][0][0];
                const v4f p1 = *(const v4f*)&red[0][j][1][0];
                const v4f p2 = *(const v4f*)&red[0][j][2][0];
                const v4f p3 = *(const v4f*)&red[0][j][3][0];
                const v4f vs = (p0 + p1) + (p2 + p3);
                if (tid == 0) *(v4f*)&lds_v[0][t * RRK] = vs;
                v4f acc = dbA[j];
                acc += vs.x * mac[0]; acc += vs.y * mac[1];
                acc += vs.z * mac[2]; acc += vs.w * mac[3];
                hA = (1.0f - ALPHA) * hA + acc;
                dbA[j] = *(const v4f*)(dpA + (size_t)((t + 4) & (TT - 1)) * HH);
                rA = tanh4(C2E * hA + tb2);
            }
            // ---- B-phase, batch B ----
            {
                const v4f p0 = *(const v4f*)&red[1][j][0][0];
                const v4f p1 = *(const v4f*)&red[1][j][1][0];
                const v4f p2 = *(const v4f*)&red[1][j][2][0];
                const v4f p3 = *(const v4f*)&red[1][j][3][0];
                const v4f vs = (p0 + p1) + (p2 + p3);
                if (tid == 64) *(v4f*)&lds_v[1][t * RRK] = vs;
                v4f acc = dbB[j];
                acc += vs.x * mac[0]; acc += vs.y * mac[1];
                acc += vs.z * mac[2]; acc += vs.w * mac[3];
                hB = (1.0f - ALPHA) * hB + acc;
                dbB[j] = *(const v4f*)(dpB + (size_t)((t + 4) & (TT - 1)) * HH);
                rB = tanh4(C2E * hB + tb2);
            }
        }
    }

    __syncthreads();

    // ---- post-pass: out_t = 0.8*out_{t-1} + sb_t + Am.v_t (chunked scan) --
    // 256 threads = 2 batches x 16 chunks x 8 cols; 64 t per chunk.
    float Amr[RRK];
    #pragma unroll
    for (int q = 0; q < RRK; ++q) Amr[q] = amy[q * 8 + oc];

    const int cg = tid >> 3;                     // 0..31
    const int sg = cg >> 4;                      // batch select 0/1
    const int cc = cg & 15;                      // chunk 0..15
    const int tc = cc * 64;
    float a64;
    {
        float a = 1.0f - ALPHA;
        #pragma unroll
        for (int k = 0; k < 6; ++k) a = a * a;   // 0.8^64
        a64 = a;
    }
    const float* sb = sbase + (size_t)(bA + sg) * (TT * OO);

    auto step_s = [&](int t) -> float {
        const v4f vv = *(const v4f*)&lds_v[sg][t * RRK];
        float s = sb[t * OO + oc];               // L2/L3-hot (pre_d just wrote)
        s = fmaf(vv.x, Amr[0], s); s = fmaf(vv.y, Amr[1], s);
        s = fmaf(vv.z, Amr[2], s); s = fmaf(vv.w, Amr[3], s);
        return s;
    };

    float L = 0.0f;
    #pragma unroll 4
    for (int jt = 0; jt < 64; ++jt)
        L = fmaf(1.0f - ALPHA, L, step_s(tc + jt));
    chs[sg][cc][oc] = L;
    block_sync_lds();
    if (tid < 16) {                              // exact serial carry per batch
        const int s2 = tid >> 3, o = tid & 7;
        float Y = amy[32 + o];                   // y_{-1} = h0 . wo'
        #pragma unroll
        for (int c2 = 0; c2 < 16; ++c2) {
            const float Lc = chs[s2][c2][o];
            chs[s2][c2][o] = Y;
            Y = fmaf(a64, Y, Lc);
        }
    }
    block_sync_lds();
    float yv = chs[sg][cc][oc];
    float* ob = out + (size_t)(bA + sg) * (TT * OO);
    #pragma unroll 4
    for (int jt = 0; jt < 64; ++jt) {
        const int t = tc + jt;
        yv = fmaf(1.0f - ALPHA, yv, step_s(t));
        ob[t * OO + oc] = yv;
    }
}

// ===========================================================================
// PATH B (fallback when workspace < 258 MB): proven round-2 kernels.
// ===========================================================================

__global__ __launch_bounds__(256)
void prew_fb(const float* __restrict__ noise, const float* __restrict__ wo,
             const float* __restrict__ so, float* __restrict__ W) {
    __shared__ __align__(16) float red[2][8][4][8];

    const int tid  = threadIdx.x;
    const int wave = tid >> 6;
    const int lane = tid & 63;
    const int e0   = tid << 2;

    float woa[4][OO];
    {
        float so8[OO];
        #pragma unroll
        for (int o = 0; o < OO; ++o) so8[o] = so[o] * NOISE_STD;
        #pragma unroll
        for (int e = 0; e < 4; ++e) {
            const float4 a4 = *(const float4*)(wo + (e0 + e) * OO);
            const float4 b4 = *(const float4*)(wo + (e0 + e) * OO + 4);
            woa[e][0] = a4.x * so8[0]; woa[e][1] = a4.y * so8[1];
            woa[e][2] = a4.z * so8[2]; woa[e][3] = a4.w * so8[3];
            woa[e][4] = b4.x * so8[4]; woa[e][5] = b4.y * so8[5];
            woa[e][6] = b4.z * so8[6]; woa[e][7] = b4.w * so8[7];
        }
    }

    const int row0 = blockIdx.x * 32;
    float4 nz[8], nzn[8];
    #pragma unroll
    for (int j = 0; j < 8; ++j)
        nz[j] = *(const float4*)(noise + (size_t)(row0 + j) * HH + e0);

    #pragma unroll
    for (int ph = 0; ph < 4; ++ph) {
        const int cur   = ph & 1;
        const int rbase = row0 + ph * 8;
        if (ph < 3) {
            #pragma unroll
            for (int j = 0; j < 8; ++j)
                nzn[j] = *(const float4*)(noise + (size_t)(rbase + 8 + j) * HH + e0);
        }
        #pragma unroll
        for (int j = 0; j < 8; ++j) {
            float op[OO];
            #pragma unroll
            for (int o = 0; o < OO; ++o)
                op[o] = fmaf(nz[j].x, woa[0][o], fmaf(nz[j].y, woa[1][o],
                        fmaf(nz[j].z, woa[2][o], nz[j].w * woa[3][o])));
            #pragma unroll
            for (int o = 0; o < OO; ++o) op[o] = wave_sum(op[o]);
            if (lane == 63) {
                *(float4*)&red[cur][j][wave][0] = make_float4(op[0], op[1], op[2], op[3]);
                *(float4*)&red[cur][j][wave][4] = make_float4(op[4], op[5], op[6], op[7]);
            }
        }
        block_sync_lds();
        if (tid < 64) {
            const int j = tid >> 3, o = tid & 7;
            W[(rbase + j) * OO + o] = (red[cur][j][0][o] + red[cur][j][1][o]) +
                                      (red[cur][j][2][o] + red[cur][j][3][o]);
        }
        #pragma unroll
        for (int j = 0; j < 8; ++j) nz[j] = nzn[j];
    }
}

__global__ __launch_bounds__(256, 1)
void rnn_fb(const float* __restrict__ x, const float* __restrict__ noise,
            const float* __restrict__ wi, const float* __restrict__ si,
            const float* __restrict__ mM, const float* __restrict__ nM,
            const float* __restrict__ bv, const float* __restrict__ wo,
            const float* __restrict__ so, const float* __restrict__ h0,
            const float* __restrict__ W, float* __restrict__ out) {
    __shared__ __align__(16) float lds_x[(TT + 1) * II];
    __shared__ __align__(16) float lds_W[TT * OO];
    __shared__ __align__(16) float lds_out[TT * OO];
    __shared__ __align__(16) float red[4][4][4];
    __shared__ __align__(16) float redc[4][104];
    __shared__ float ambx[104];

    const int tid  = threadIdx.x;
    const int b    = blockIdx.x;
    const int wave = tid >> 6;
    const int lane = tid & 63;
    const int e0   = tid << 2;
    const int oc   = tid & 7;

    {
        const float4* sx = (const float4*)(x + (size_t)b * (TT * II));
        const float4* sw = (const float4*)(W + (size_t)b * (TT * OO));
        float4* dx = (float4*)lds_x;
        float4* dw = (float4*)lds_W;
        #pragma unroll
        for (int k = 0; k < 8; ++k) {
            dx[k * 256 + tid] = sx[k * 256 + tid];
            dw[k * 256 + tid] = sw[k * 256 + tid];
        }
        if (tid < 2) dx[2048 + tid] = sx[2046 + tid];
    }

    float wia[II][4];
    v4f   wiac[II];
    #pragma unroll
    for (int i = 0; i < II; ++i) {
        const float s  = ALPHA * si[i];
        const float4 w = *(const float4*)(wi + i * HH + e0);
        wia[i][0] = w.x * s; wia[i][1] = w.y * s; wia[i][2] = w.z * s; wia[i][3] = w.w * s;
        wiac[i] = (v4f){wia[i][0], wia[i][1], wia[i][2], wia[i][3]};
    }
    float ma[4][RRK];
    v4f   nrv[4];
    v4f   mac[RRK];
    #pragma unroll
    for (int e = 0; e < 4; ++e) {
        const float4 m4 = *(const float4*)(mM + (e0 + e) * RRK);
        const float4 n4 = *(const float4*)(nM + (e0 + e) * RRK);
        const float cs = ALPHA / (float)HH;
        ma[e][0] = m4.x * cs; ma[e][1] = m4.y * cs; ma[e][2] = m4.z * cs; ma[e][3] = m4.w * cs;
        nrv[e] = (v4f){n4.x, n4.y, n4.z, n4.w};
    }
    #pragma unroll
    for (int q = 0; q < RRK; ++q)
        mac[q] = (v4f){ma[0][q], ma[1][q], ma[2][q], ma[3][q]};

    float woa[4][OO];
    {
        #pragma unroll
        for (int e = 0; e < 4; ++e) {
            const float4 a4 = *(const float4*)(wo + (e0 + e) * OO);
            const float4 b4 = *(const float4*)(wo + (e0 + e) * OO + 4);
            woa[e][0] = a4.x * so[0]; woa[e][1] = a4.y * so[1];
            woa[e][2] = a4.z * so[2]; woa[e][3] = a4.w * so[3];
            woa[e][4] = b4.x * so[4]; woa[e][5] = b4.y * so[5];
            woa[e][6] = b4.z * so[6]; woa[e][7] = b4.w * so[7];
        }
    }
    v4f tb2e, h, rr;
    {
        const v4f b4 = *(const v4f*)(bv + e0);
        tb2e = C2E * b4;
        h = *(const v4f*)(h0 + e0);
        v4f targ = C2E * h;
        rr.x = tanh_from_l2x(targ.x); rr.y = tanh_from_l2x(targ.y);
        rr.z = tanh_from_l2x(targ.z); rr.w = tanh_from_l2x(targ.w);
    }

    #pragma unroll
    for (int kg = 0; kg < 26; ++kg) {
        float p[4];
        #pragma unroll
        for (int u = 0; u < 4; ++u) {
            const int k = kg * 4 + u;
            float s;
            if (k < 32) {
                const int q = k >> 3, o = k & 7;
                s = fmaf(ma[0][q], woa[0][o], fmaf(ma[1][q], woa[1][o],
                    fmaf(ma[2][q], woa[2][o], ma[3][q] * woa[3][o])));
            } else if (k < 96) {
                const int i = (k - 32) >> 3, o = k & 7;
                s = fmaf(wia[i][0], woa[0][o], fmaf(wia[i][1], woa[1][o],
                    fmaf(wia[i][2], woa[2][o], wia[i][3] * woa[3][o])));
            } else {
                const int o = k - 96;
                s = fmaf(h.x, woa[0][o], fmaf(h.y, woa[1][o],
                    fmaf(h.z, woa[2][o], h.w * woa[3][o])));
            }
            p[u] = wave_sum(s);
        }
        if (lane == 63)
            *(float4*)&redc[wave][kg * 4] = make_float4(p[0], p[1], p[2], p[3]);
    }
    block_sync_lds();
    if (tid < 104)
        ambx[tid] = (redc[0][tid] + redc[1][tid]) + (redc[2][tid] + redc[3][tid]);
    __syncthreads();

    float Amr[RRK], Bxr[II], y;
    #pragma unroll
    for (int q = 0; q < RRK; ++q) Amr[q] = ambx[q * 8 + oc];
    #pragma unroll
    for (int i = 0; i < II; ++i) Bxr[i] = ambx[32 + i * 8 + oc];
    y = ambx[96 + oc];

    const float* nzp = noise + (size_t)b * (TT * HH) + e0;
    v4f nzb[4];
    #pragma unroll
    for (int j = 0; j < 4; ++j) nzb[j] = *(const v4f*)(nzp + j * HH);

    v4f xqc0 = *(const v4f*)&lds_x[0];
    v4f xqc1 = *(const v4f*)&lds_x[4];
    float wqc = lds_W[oc];

    for (int t0 = 0; t0 < TT; t0 += 4) {
        #pragma unroll
        for (int j = 0; j < 4; ++j) {
            const int t = t0 + j;
            const int tn = t + 1;
            const v4f xqn0 = *(const v4f*)&lds_x[tn * II];
            const v4f xqn1 = *(const v4f*)&lds_x[tn * II + 4];
            const float wqn = lds_W[(tn & (TT - 1)) * OO + oc];

            v4f vpv = rr.x * nrv[0];
            vpv += rr.y * nrv[1];
            vpv += rr.z * nrv[2];
            vpv += rr.w * nrv[3];
            float vp0 = wave_sum(vpv.x);
            float vp1 = wave_sum(vpv.y);
            float vp2 = wave_sum(vpv.z);
            float vp3 = wave_sum(vpv.w);
            if (lane == 63)
                *(float4*)&red[j][wave][0] = make_float4(vp0, vp1, vp2, vp3);

            float ybase = fmaf(xqc0.x, Bxr[0], wqc);
            ybase = fmaf(xqc0.y, Bxr[1], ybase);
            ybase = fmaf(xqc0.z, Bxr[2], ybase);
            ybase = fmaf(xqc0.w, Bxr[3], ybase);
            ybase = fmaf(xqc1.x, Bxr[4], ybase);
            ybase = fmaf(xqc1.y, Bxr[5], ybase);
            ybase = fmaf(xqc1.z, Bxr[6], ybase);
            ybase = fmaf(xqc1.w, Bxr[7], ybase);

            v4f auv = xqc0.x * wiac[0];
            auv += xqc0.y * wiac[1];
            auv += xqc0.z * wiac[2];
            auv += xqc0.w * wiac[3];
            auv += xqc1.x * wiac[4];
            auv += xqc1.y * wiac[5];
            auv += xqc1.z * wiac[6];
            auv += xqc1.w * wiac[7];

            block_sync_lds();

            const v4f s0 = *(const v4f*)&red[j][0][0];
            const v4f s1 = *(const v4f*)&red[j][1][0];
            const v4f s2 = *(const v4f*)&red[j][2][0];
            const v4f s3 = *(const v4f*)&red[j][3][0];
            const v4f vs = (s0 + s1) + (s2 + s3);

            v4f acc = auv;
            acc += vs.x * mac[0];
            acc += vs.y * mac[1];
            acc += vs.z * mac[2];
            acc += vs.w * mac[3];
            h = (1.0f - ALPHA) * h + acc;
            h += NOISE_STD * nzb[j];

            {
                float t4 = fmaf(vs.x, Amr[0], ybase);
                t4 = fmaf(vs.y, Amr[1], t4);
                t4 = fmaf(vs.z, Amr[2], t4);
                t4 = fmaf(vs.w, Amr[3], t4);
                y = fmaf(1.0f - ALPHA, y, t4);
                if (tid < OO) lds_out[t * OO + tid] = y;
            }

            nzb[j] = *(const v4f*)(nzp + ((t + 4) & (TT - 1)) * HH);

            {
                v4f targ = C2E * h + tb2e;
                rr.x = tanh_from_l2x(targ.x);
                rr.y = tanh_from_l2x(targ.y);
                rr.z = tanh_from_l2x(targ.z);
                rr.w = tanh_from_l2x(targ.w);
            }
            xqc0 = xqn0; xqc1 = xqn1; wqc = wqn;
        }
    }

    __syncthreads();
    {
        float4* dst = (float4*)(out + (size_t)b * (TT * OO));
        const float4* srcv = (const float4*)lds_out;
        #pragma unroll
        for (int k = 0; k < 8; ++k)
            dst[k * 256 + tid] = srcv[k * 256 + tid];
    }
}

extern "C" void kernel_launch(void* const* d_in, const int* in_sizes, int n_in,
                              void* d_out, int out_size, void* d_ws, size_t ws_size,
                              hipStream_t stream) {
    const float* x     = (const float*)d_in[0];
    const float* noise = (const float*)d_in[1];
    const float* wi    = (const float*)d_in[2];
    const float* si    = (const float*)d_in[3];
    const float* mM    = (const float*)d_in[4];
    const float* nM    = (const float*)d_in[5];
    const float* bv    = (const float*)d_in[6];
    const float* wo    = (const float*)d_in[7];
    const float* so    = (const float*)d_in[8];
    const float* h0    = (const float*)d_in[9];
    float* out = (float*)d_out;

    const size_t needD = (size_t)BB * TT * HH * sizeof(float);   // 256 MB
    const size_t needS = (size_t)BB * TT * OO * sizeof(float);   // 2 MB

    if (ws_size >= needD + needS) {
        float* dbuf = (float*)d_ws;
        float* sb   = dbuf + (size_t)BB * TT * HH;
        pre_d_kernel<<<dim3(2048), dim3(256), 0, stream>>>(
            x, noise, wi, si, wo, so, dbuf, sb);
        rnn_pair2<<<dim3(BB / 2), dim3(256), 0, stream>>>(
            dbuf, sb, mM, nM, bv, wo, so, h0, out);
    } else {
        float* W = (float*)d_ws;   // 2 MB
        prew_fb<<<dim3(2048), dim3(256), 0, stream>>>(noise, wo, so, W);
        rnn_fb<<<dim3(BB), dim3(256), 0, stream>>>(
            x, noise, wi, si, mM, nM, bv, wo, so, h0, W, out);
    }
}